// Round 8
// baseline (216.557 us; speedup 1.0000x reference)
//
#include <hip/hip_runtime.h>
#include <hip/hip_bf16.h>
#include <math.h>

#define Bc  2
#define Sc  2048
#define Dc  1024
#define Hc  16
#define DHc 64
#define QSCALE 0.1803368801111244f   // DH^-0.5 * log2(e)  (exp -> exp2)

typedef __attribute__((ext_vector_type(8))) short short8;   // 8 x bf16
typedef __attribute__((ext_vector_type(4))) float f32x4;    // MFMA accumulator

__device__ inline f32x4 mfma16(short8 a, short8 b, f32x4 c) {
    return __builtin_amdgcn_mfma_f32_16x16x32_bf16(a, b, c, 0, 0, 0);
}

typedef __attribute__((address_space(1))) const unsigned int g_u32;
typedef __attribute__((address_space(3))) unsigned int l_u32;
__device__ inline void gld16(const void* g, void* l) {
    __builtin_amdgcn_global_load_lds((g_u32*)g, (l_u32*)l, 16, 0, 0);
}

__device__ inline float fast_exp2(float x) { return __builtin_amdgcn_exp2f(x); }

__device__ inline short8 cvt8(float4 a, float4 b) {
    union { __hip_bfloat16 h[8]; short8 s; } u;
    u.h[0] = __float2bfloat16(a.x); u.h[1] = __float2bfloat16(a.y);
    u.h[2] = __float2bfloat16(a.z); u.h[3] = __float2bfloat16(a.w);
    u.h[4] = __float2bfloat16(b.x); u.h[5] = __float2bfloat16(b.y);
    u.h[6] = __float2bfloat16(b.z); u.h[7] = __float2bfloat16(b.w);
    return u.s;
}

// ---------------- cast: 4 weights [1024x1024] + 3 inputs [4096x1024] fp32 -> bf16 ----------------
__global__ __launch_bounds__(256) void castall_k(const float* __restrict__ W0, const float* __restrict__ W1,
                                                 const float* __restrict__ W2, const float* __restrict__ W3,
                                                 const float* __restrict__ I0, const float* __restrict__ I1,
                                                 const float* __restrict__ I2,
                                                 __hip_bfloat16* o0, __hip_bfloat16* o1,
                                                 __hip_bfloat16* o2, __hip_bfloat16* o3,
                                                 __hip_bfloat16* o4, __hip_bfloat16* o5,
                                                 __hip_bfloat16* o6)
{
    const int y = blockIdx.y;
    const float* s; __hip_bfloat16* d; size_t n;
    switch (y) {
        case 0: s = W0; d = o0; n = 1u << 20; break;
        case 1: s = W1; d = o1; n = 1u << 20; break;
        case 2: s = W2; d = o2; n = 1u << 20; break;
        case 3: s = W3; d = o3; n = 1u << 20; break;
        case 4: s = I0; d = o4; n = 1u << 22; break;
        case 5: s = I1; d = o5; n = 1u << 22; break;
        default: s = I2; d = o6; n = 1u << 22; break;
    }
    size_t idx = ((size_t)blockIdx.x * 256 + threadIdx.x) * 8;
    if (idx >= n) return;
    float4 a = *(const float4*)(s + idx);
    float4 b = *(const float4*)(s + idx + 4);
    *(short8*)(d + idx) = cvt8(a, b);
}

// ---------------- fused QKV projection (pure bf16, m97 2-barrier) ----------------
// 768 blocks: p = blockIdx>>8 selects {Q,K,V}. 128x128 tile, BK=64, single-buffer 32KB LDS.
// q output pre-scaled by DH^-0.5 * log2(e).
__global__ __launch_bounds__(256, 3) void qkv_k(const __hip_bfloat16* __restrict__ Qb,
                                                const __hip_bfloat16* __restrict__ Kb,
                                                const __hip_bfloat16* __restrict__ Vb,
                                                const __hip_bfloat16* __restrict__ Wqb,
                                                const __hip_bfloat16* __restrict__ Wkb,
                                                const __hip_bfloat16* __restrict__ Wvb,
                                                const float* __restrict__ bq, const float* __restrict__ bk,
                                                const float* __restrict__ bv,
                                                __hip_bfloat16* __restrict__ qo, __hip_bfloat16* __restrict__ ko,
                                                __hip_bfloat16* __restrict__ vto)
{
    __shared__ __align__(16) __hip_bfloat16 As[128 * 64];
    __shared__ __align__(16) __hip_bfloat16 Bs[128 * 64];
    const int p   = blockIdx.x >> 8;
    const int blk = blockIdx.x & 255;
    const int bm  = blk & 31, bn = blk >> 5;
    const __hip_bfloat16* A = p == 0 ? Qb : p == 1 ? Kb : Vb;
    const __hip_bfloat16* W = p == 0 ? Wqb : p == 1 ? Wkb : Wvb;
    const float* bias = p == 0 ? bq : p == 1 ? bk : bv;

    const int tid = threadIdx.x, wave = tid >> 6, lane = tid & 63;
    const int quad = lane >> 4, l15 = lane & 15;
    const int wm = wave >> 1, wn = wave & 1;
    const int sw = l15 & 7;

    f32x4 acc[4][4] = {};

#pragma unroll
    for (int i = 0; i < 4; ++i) {
        int c = wave * 64 + i * 256 + lane;
        int row = c >> 3, g = (c & 7) ^ (row & 7);
        gld16(A + (size_t)(bm * 128 + row) * 1024 + g * 8, (char*)As + (size_t)c * 16);
        gld16(W + (size_t)(bn * 128 + row) * 1024 + g * 8, (char*)Bs + (size_t)c * 16);
    }

    for (int kki = 0; kki < 16; ++kki) {
        __syncthreads();   // barrier 1: DMA drained, prev readers done

        short8 af[4][2], bf2[4][2];
#pragma unroll
        for (int mi = 0; mi < 4; ++mi)
#pragma unroll
            for (int h = 0; h < 2; ++h)
                af[mi][h] = *(const short8*)((char*)As + (size_t)(wm * 64 + mi * 16 + l15) * 128 +
                                             ((((h << 2) + quad) ^ sw) << 4));
#pragma unroll
        for (int ni = 0; ni < 4; ++ni)
#pragma unroll
            for (int h = 0; h < 2; ++h)
                bf2[ni][h] = *(const short8*)((char*)Bs + (size_t)(wn * 64 + ni * 16 + l15) * 128 +
                                              ((((h << 2) + quad) ^ sw) << 4));

        __syncthreads();   // barrier 2: all waves have their fragments

        if (kki < 15) {
            const int kk2 = (kki + 1) * 64;
#pragma unroll
            for (int i = 0; i < 4; ++i) {
                int c = wave * 64 + i * 256 + lane;
                int row = c >> 3, g = (c & 7) ^ (row & 7);
                gld16(A + (size_t)(bm * 128 + row) * 1024 + kk2 + g * 8, (char*)As + (size_t)c * 16);
                gld16(W + (size_t)(bn * 128 + row) * 1024 + kk2 + g * 8, (char*)Bs + (size_t)c * 16);
            }
        }

#pragma unroll
        for (int mi = 0; mi < 4; ++mi)
#pragma unroll
            for (int ni = 0; ni < 4; ++ni) {
                acc[mi][ni] = mfma16(af[mi][0], bf2[ni][0], acc[mi][ni]);
                acc[mi][ni] = mfma16(af[mi][1], bf2[ni][1], acc[mi][ni]);
            }
    }

    float bvv[4];
#pragma unroll
    for (int ni = 0; ni < 4; ++ni) bvv[ni] = bias[bn * 128 + wn * 64 + ni * 16 + l15];
#pragma unroll
    for (int mi = 0; mi < 4; ++mi) {
#pragma unroll
        for (int r = 0; r < 4; ++r) {
            int m = bm * 128 + wm * 64 + mi * 16 + quad * 4 + r;
            int b_ = m >> 11, s_ = m & 2047;
#pragma unroll
            for (int ni = 0; ni < 4; ++ni) {
                int n = bn * 128 + wn * 64 + ni * 16 + l15;
                int h_ = n >> 6, d_ = n & 63;
                float val = acc[mi][ni][r] + bvv[ni];
                if (p == 0) val *= QSCALE;          // fold scale*log2e into q
                __hip_bfloat16 hv = __float2bfloat16(val);
                if (p < 2) {
                    __hip_bfloat16* dst = (p == 0 ? qo : ko);
                    dst[((size_t)(b_ * Hc + h_) * Sc + s_) * DHc + d_] = hv;
                } else {
                    // head-transposed + pi-permuted within 64-key tiles: pi(loc) = (loc&15)*4 + (loc>>4)
                    int loc = s_ & 63;
                    int sp = (s_ & ~63) | ((loc & 15) << 2) | (loc >> 4);
                    vto[((size_t)(b_ * Hc + h_) * DHc + d_) * Sc + sp] = hv;
                }
            }
        }
    }
}

// ---------------- flash attention, split-K x2 ----------------
// 1024 blocks: bh = blk&31, kp = (blk>>5)&1 (key parity), qt = 15-(blk>>6) (heavy first).
// Block processes 64-key tiles g = kp, kp+2, ..., kp+2*qt for q-rows [qt*128, qt*128+128).
// Unnormalized bf16 O-partials + f32 lsum written to obP/lsP; combine_k merges.
__global__ __launch_bounds__(256, 3) void attn_k(const __hip_bfloat16* __restrict__ qb,
                                                 const __hip_bfloat16* __restrict__ kb,
                                                 const __hip_bfloat16* __restrict__ vtb,
                                                 const int* __restrict__ mask,
                                                 __hip_bfloat16* __restrict__ obE,
                                                 __hip_bfloat16* __restrict__ obO,
                                                 float* __restrict__ lsE,
                                                 float* __restrict__ lsO)
{
    __shared__ __align__(16) __hip_bfloat16 Klds[2][64 * 64];
    __shared__ __align__(16) __hip_bfloat16 Vlds[2][64 * 64];
    __shared__ __align__(16) __hip_bfloat16 Plds[4][32 * 72];   // row stride 144B

    const int bh = blockIdx.x & 31;
    const int kp = (blockIdx.x >> 5) & 1;
    const int qt = 15 - (blockIdx.x >> 6);
    const int b  = bh >> 4;
    const int tid = threadIdx.x, wave = tid >> 6, lane = tid & 63;
    const int quad = lane >> 4, l15 = lane & 15;
    const int sw = l15 & 7;
    const int r0 = qt * 128 + wave * 32;      // wave's first q row

    const __hip_bfloat16* qh  = qb  + (size_t)bh * Sc * DHc;
    const __hip_bfloat16* kh  = kb  + (size_t)bh * Sc * DHc;
    const __hip_bfloat16* vth = vtb + (size_t)bh * DHc * Sc;
    __hip_bfloat16* obP = kp ? obO : obE;
    float*           lsP = kp ? lsO : lsE;

    short8 qf[2][2];
#pragma unroll
    for (int rc = 0; rc < 2; ++rc)
#pragma unroll
        for (int h = 0; h < 2; ++h)
            qf[rc][h] = *(const short8*)(qh + (size_t)(r0 + rc * 16 + l15) * DHc + h * 32 + quad * 8);

    f32x4 O[2][4] = {};
    float lsum[2][4] = {};

    // stage tile g0 = kp -> buf 0
    {
        const int kv = kp * 64;
#pragma unroll
        for (int i = 0; i < 2; ++i) {
            int c = i * 256 + wave * 64 + lane;
            int row = c >> 3, g = (c & 7) ^ (row & 7);
            gld16(kh + (size_t)(kv + row) * DHc + g * 8, (char*)&Klds[0][0] + (size_t)c * 16);
            gld16(vth + (size_t)row * Sc + kv + g * 8, (char*)&Vlds[0][0] + (size_t)c * 16);
        }
    }

    for (int j = 0; j <= qt; ++j) {
        __syncthreads();   // tile j's DMA drained (vmcnt(0)), all waves synced
        if (j < qt) {
            const int kv1 = (kp + 2 * (j + 1)) * 64, nb = (j + 1) & 1;
#pragma unroll
            for (int i = 0; i < 2; ++i) {
                int c = i * 256 + wave * 64 + lane;
                int row = c >> 3, g = (c & 7) ^ (row & 7);
                gld16(kh + (size_t)(kv1 + row) * DHc + g * 8, (char*)&Klds[nb][0] + (size_t)c * 16);
                gld16(vth + (size_t)row * Sc + kv1 + g * 8, (char*)&Vlds[nb][0] + (size_t)c * 16);
            }
        }
        const int kv0 = (kp + 2 * j) * 64, buf = j & 1;
        if (kv0 >= r0 + 32) continue;          // fully-masked for this wave

        // QK^T: 32 q-rows x 64 keys; kf reused across both row chunks
        f32x4 sc[2][4] = {};
#pragma unroll
        for (int h = 0; h < 2; ++h)
#pragma unroll
            for (int nc = 0; nc < 4; ++nc) {
                short8 kf = *(const short8*)((char*)&Klds[buf][0] +
                            (size_t)(nc * 16 + l15) * 128 + ((((h << 2) + quad) ^ sw) << 4));
                sc[0][nc] = mfma16(qf[0][h], kf, sc[0][nc]);
                sc[1][nc] = mfma16(qf[1][h], kf, sc[1][nc]);
            }

        float mb[4];
#pragma unroll
        for (int nc = 0; nc < 4; ++nc)
            mb[nc] = mask[b * Sc + kv0 + nc * 16 + l15] ? 0.f : -__builtin_inff();

        if (kv0 + 64 > r0) {
            // diagonal region: causal test needed
#pragma unroll
            for (int rc = 0; rc < 2; ++rc)
#pragma unroll
                for (int r = 0; r < 4; ++r) {
                    const int q_idx = r0 + rc * 16 + quad * 4 + r;
                    float pv[4], ps = 0.f;
#pragma unroll
                    for (int nc = 0; nc < 4; ++nc) {
                        int key = kv0 + nc * 16 + l15;
                        float s = sc[rc][nc][r] + mb[nc];
                        s = (key <= q_idx) ? s : -__builtin_inff();
                        pv[nc] = fast_exp2(fminf(s, 43.f));
                        ps += pv[nc];
                    }
                    lsum[rc][r] += ps;
                    union { __hip_bfloat16 h[4]; unsigned long long u; } pp;
#pragma unroll
                    for (int nc = 0; nc < 4; ++nc) pp.h[nc] = __float2bfloat16(pv[nc]);
                    *(unsigned long long*)((char*)&Plds[wave][0] +
                        (size_t)(rc * 16 + quad * 4 + r) * 144 + l15 * 8) = pp.u;
                }
        } else {
            // full tile: no causal test
#pragma unroll
            for (int rc = 0; rc < 2; ++rc)
#pragma unroll
                for (int r = 0; r < 4; ++r) {
                    float pv[4], ps = 0.f;
#pragma unroll
                    for (int nc = 0; nc < 4; ++nc) {
                        float s = sc[rc][nc][r] + mb[nc];
                        pv[nc] = fast_exp2(fminf(s, 43.f));
                        ps += pv[nc];
                    }
                    lsum[rc][r] += ps;
                    union { __hip_bfloat16 h[4]; unsigned long long u; } pp;
#pragma unroll
                    for (int nc = 0; nc < 4; ++nc) pp.h[nc] = __float2bfloat16(pv[nc]);
                    *(unsigned long long*)((char*)&Plds[wave][0] +
                        (size_t)(rc * 16 + quad * 4 + r) * 144 + l15 * 8) = pp.u;
                }
        }

        // PV: vf reused across both row chunks
#pragma unroll
        for (int h = 0; h < 2; ++h) {
            short8 pf0 = *(const short8*)((char*)&Plds[wave][0] + (size_t)l15 * 144 + h * 64 + quad * 16);
            short8 pf1 = *(const short8*)((char*)&Plds[wave][0] + (size_t)(16 + l15) * 144 + h * 64 + quad * 16);
#pragma unroll
            for (int nc = 0; nc < 4; ++nc) {
                short8 vf = *(const short8*)((char*)&Vlds[buf][0] +
                            (size_t)(nc * 16 + l15) * 128 + ((((h << 2) + quad) ^ sw) << 4));
                O[0][nc] = mfma16(pf0, vf, O[0][nc]);
                O[1][nc] = mfma16(pf1, vf, O[1][nc]);
            }
        }
    }

    // epilogue: reduce lsum across 16 lanes, store unnormalized partials
#pragma unroll
    for (int rc = 0; rc < 2; ++rc)
#pragma unroll
        for (int r = 0; r < 4; ++r) {
            float l = lsum[rc][r];
#pragma unroll
            for (int off = 1; off < 16; off <<= 1) l += __shfl_xor(l, off);
            const int q_idx = r0 + rc * 16 + quad * 4 + r;
            if (l15 == 0) lsP[(size_t)bh * Sc + q_idx] = l;
#pragma unroll
            for (int nc = 0; nc < 4; ++nc)
                obP[((size_t)bh * Sc + q_idx) * DHc + nc * 16 + l15] =
                    __float2bfloat16(O[rc][nc][r]);
        }
}

// ---------------- combine split-K partials: out = (Oe+Oo)/(le+lo), bf16 head-split ----------------
__global__ __launch_bounds__(256) void combine_k(const __hip_bfloat16* __restrict__ Oe,
                                                 const __hip_bfloat16* __restrict__ Oo,
                                                 const float* __restrict__ le,
                                                 const float* __restrict__ lo,
                                                 __hip_bfloat16* __restrict__ out)
{
    size_t t = (size_t)blockIdx.x * 256 + threadIdx.x;   // 524288 threads, 8 elems each
    size_t row = t >> 3;
    float inv = 1.f / (le[row] + lo[row]);
    union { short8 s; __hip_bfloat16 h[8]; } ua, ub, uo;
    ua.s = *(const short8*)(Oe + t * 8);
    ub.s = *(const short8*)(Oo + t * 8);
#pragma unroll
    for (int i = 0; i < 8; ++i)
        uo.h[i] = __float2bfloat16((__bfloat162float(ua.h[i]) + __bfloat162float(ub.h[i])) * inv);
    *(short8*)(out + t * 8) = uo.s;
}

// ---------------- output projection (m97 2-barrier, 128x128): [4096x1024] = A @ Wo^T + bo ----
// 256 blocks; single-buffer 32KB LDS, both operands DMA.
__global__ __launch_bounds__(256, 3) void out_k(const __hip_bfloat16* __restrict__ Ab,
                                                const __hip_bfloat16* __restrict__ Wb,
                                                const float* __restrict__ bias,
                                                float* __restrict__ outp)
{
    __shared__ __align__(16) __hip_bfloat16 As[128 * 64];
    __shared__ __align__(16) __hip_bfloat16 Bs[128 * 64];
    const int bm = blockIdx.x & 31, bn = blockIdx.x >> 5;   // bn 0..7
    const int tid = threadIdx.x, wave = tid >> 6, lane = tid & 63;
    const int quad = lane >> 4, l15 = lane & 15;
    const int wm = wave >> 1, wn = wave & 1;
    const int sw = l15 & 7;

    f32x4 acc[4][4] = {};

    // prologue: DMA k-block 0 (head h=0)
#pragma unroll
    for (int i = 0; i < 4; ++i) {
        int c = wave * 64 + i * 256 + lane;
        int row = c >> 3, g = (c & 7) ^ (row & 7);
        int m = bm * 128 + row, b_ = m >> 11, s_ = m & 2047;
        gld16(Ab + (((size_t)(b_ * Hc) * Sc + s_) * DHc + g * 8), (char*)As + (size_t)c * 16);
        gld16(Wb + (size_t)(bn * 128 + row) * 1024 + g * 8, (char*)Bs + (size_t)c * 16);
    }

    for (int kki = 0; kki < 16; ++kki) {
        __syncthreads();   // barrier 1: DMA drained

        short8 af[4][2], bf2[4][2];
#pragma unroll
        for (int mi = 0; mi < 4; ++mi)
#pragma unroll
            for (int h = 0; h < 2; ++h)
                af[mi][h] = *(const short8*)((char*)As + (size_t)(wm * 64 + mi * 16 + l15) * 128 +
                                             ((((h << 2) + quad) ^ sw) << 4));
#pragma unroll
        for (int ni = 0; ni < 4; ++ni)
#pragma unroll
            for (int h = 0; h < 2; ++h)
                bf2[ni][h] = *(const short8*)((char*)Bs + (size_t)(wn * 64 + ni * 16 + l15) * 128 +
                                              ((((h << 2) + quad) ^ sw) << 4));

        __syncthreads();   // barrier 2: fragments in regs

        if (kki < 15) {
            const int h2 = kki + 1, kk2 = h2 * 64;
#pragma unroll
            for (int i = 0; i < 4; ++i) {
                int c = wave * 64 + i * 256 + lane;
                int row = c >> 3, g = (c & 7) ^ (row & 7);
                int m = bm * 128 + row, b_ = m >> 11, s_ = m & 2047;
                gld16(Ab + (((size_t)(b_ * Hc + h2) * Sc + s_) * DHc + g * 8), (char*)As + (size_t)c * 16);
                gld16(Wb + (size_t)(bn * 128 + row) * 1024 + kk2 + g * 8, (char*)Bs + (size_t)c * 16);
            }
        }

#pragma unroll
        for (int mi = 0; mi < 4; ++mi)
#pragma unroll
            for (int ni = 0; ni < 4; ++ni) {
                acc[mi][ni] = mfma16(af[mi][0], bf2[ni][0], acc[mi][ni]);
                acc[mi][ni] = mfma16(af[mi][1], bf2[ni][1], acc[mi][ni]);
            }
    }

    float bvv[4];
#pragma unroll
    for (int ni = 0; ni < 4; ++ni) bvv[ni] = bias[bn * 128 + wn * 64 + ni * 16 + l15];
#pragma unroll
    for (int mi = 0; mi < 4; ++mi)
#pragma unroll
        for (int r = 0; r < 4; ++r) {
            int m = bm * 128 + wm * 64 + mi * 16 + quad * 4 + r;
#pragma unroll
            for (int ni = 0; ni < 4; ++ni) {
                int n = bn * 128 + wn * 64 + ni * 16 + l15;
                outp[(size_t)m * 1024 + n] = acc[mi][ni][r] + bvv[ni];
            }
        }
}

extern "C" void kernel_launch(void* const* d_in, const int* in_sizes, int n_in,
                              void* d_out, int out_size, void* d_ws, size_t ws_size,
                              hipStream_t stream) {
    const float* Q   = (const float*)d_in[0];
    const float* K   = (const float*)d_in[1];
    const float* V   = (const float*)d_in[2];
    const int*  mask = (const int*)d_in[3];
    const float* Wq  = (const float*)d_in[4];
    const float* bq  = (const float*)d_in[5];
    const float* Wk  = (const float*)d_in[6];
    const float* bk  = (const float*)d_in[7];
    const float* Wv  = (const float*)d_in[8];
    const float* bv  = (const float*)d_in[9];
    const float* Wo  = (const float*)d_in[10];
    const float* bo  = (const float*)d_in[11];

    char* ws = (char*)d_ws;
    __hip_bfloat16* wqb = (__hip_bfloat16*)(ws);                  // 2MB
    __hip_bfloat16* wkb = (__hip_bfloat16*)(ws + (2u << 20));     // 2MB
    __hip_bfloat16* wvb = (__hip_bfloat16*)(ws + (4u << 20));     // 2MB
    __hip_bfloat16* wob = (__hip_bfloat16*)(ws + (6u << 20));     // 2MB
    __hip_bfloat16* qbuf  = (__hip_bfloat16*)(ws + (8u << 20));   // 8MB (attn out after combine)
    __hip_bfloat16* kbuf  = (__hip_bfloat16*)(ws + (16u << 20));  // 8MB
    __hip_bfloat16* vtbuf = (__hip_bfloat16*)(ws + (24u << 20));  // 8MB
    __hip_bfloat16* Qbf   = (__hip_bfloat16*)(ws + (32u << 20));  // 8MB, reused as Oe
    __hip_bfloat16* Kbf   = (__hip_bfloat16*)(ws + (40u << 20));  // 8MB, reused as Oo
    __hip_bfloat16* Vbf   = (__hip_bfloat16*)(ws + (48u << 20));  // 8MB, reused as lsums
    __hip_bfloat16* Oe    = Qbf;
    __hip_bfloat16* Oo    = Kbf;
    float* lsE = (float*)(ws + (48u << 20));                      // 256KB
    float* lsO = (float*)(ws + (48u << 20) + (256u << 10));       // 256KB

    castall_k<<<dim3(2048, 7), 256, 0, stream>>>(Wq, Wk, Wv, Wo, Q, K, V,
                                                 wqb, wkb, wvb, wob, Qbf, Kbf, Vbf);
    qkv_k<<<768, 256, 0, stream>>>(Qbf, Kbf, Vbf, wqb, wkb, wvb, bq, bk, bv, qbuf, kbuf, vtbuf);
    attn_k<<<1024, 256, 0, stream>>>(qbuf, kbuf, vtbuf, mask, Oe, Oo, lsE, lsO);
    combine_k<<<2048, 256, 0, stream>>>(Oe, Oo, lsE, lsO, qbuf);
    out_k<<<256, 256, 0, stream>>>(qbuf, wob, bo, (float*)d_out);
}